// Round 1
// baseline (137.143 us; speedup 1.0000x reference)
//
#include <hip/hip_runtime.h>

#define BH 8
#define W 512
#define H 512
#define NPLANES 48            // 16 batches * 3 channels
#define NPIX (16.0f*3.0f*512.0f*512.0f)

__global__ __launch_bounds__(256) void ssim_main(const float* __restrict__ pred,
                                                 const float* __restrict__ targ,
                                                 const float* __restrict__ win,
                                                 float* __restrict__ acc) {
    const int tid = threadIdx.x;
    const int strip = blockIdx.x & 63;       // 512/BH = 64 strips per plane
    const int nc = blockIdx.x >> 6;          // plane index 0..47
    const int y0 = strip * BH;
    const float* P = pred + (size_t)nc * (W * H);
    const float* T = targ + (size_t)nc * (W * H);

    // Recover the 1D gaussian from the 2D window: w2d[5][i] = g[5]*g[i],
    // w2d[5][5] = g[5]^2  ->  g[i] = w2d[5][i]/sqrt(w2d[5][5]).
    float g[11];
    {
        float g5 = sqrtf(win[5 * 11 + 5]);
        #pragma unroll
        for (int i = 0; i < 11; ++i) g[i] = win[5 * 11 + i] / g5;
    }

    // Row staging, zero-padded by 5 on each side (index x+5 for column x).
    __shared__ float sp[W + 10], st[W + 10];
    if (tid < 5) {
        sp[tid] = 0.f; st[tid] = 0.f;
        sp[W + 5 + tid] = 0.f; st[W + 5 + tid] = 0.f;
    }

    // Per-thread accumulators: 5 fields x BH rows x 2 columns (tid, tid+256).
    float a0[BH][2], a1[BH][2], a2[BH][2], a3[BH][2], a4[BH][2];
    #pragma unroll
    for (int r = 0; r < BH; ++r)
        #pragma unroll
        for (int j = 0; j < 2; ++j) {
            a0[r][j] = 0.f; a1[r][j] = 0.f; a2[r][j] = 0.f;
            a3[r][j] = 0.f; a4[r][j] = 0.f;
        }

    for (int iy = y0 - 5; iy <= y0 + BH + 4; ++iy) {
        if (iy < 0 || iy >= H) continue;   // zero padding rows: contribute 0 (uniform branch)
        __syncthreads();                   // protect sp/st from previous iteration's readers
        const float* prow = P + iy * W;
        const float* trow = T + iy * W;
        sp[5 + tid]       = prow[tid];
        sp[5 + tid + 256] = prow[tid + 256];
        st[5 + tid]       = trow[tid];
        st[5 + tid + 256] = trow[tid + 256];
        __syncthreads();

        // Horizontal 11-tap pass for this row, 5 fields, 2 columns per thread.
        float h0[2] = {0.f, 0.f}, h1[2] = {0.f, 0.f}, h2[2] = {0.f, 0.f},
              h3[2] = {0.f, 0.f}, h4[2] = {0.f, 0.f};
        #pragma unroll
        for (int k = 0; k < 11; ++k) {
            float w = g[k];
            #pragma unroll
            for (int j = 0; j < 2; ++j) {
                int x = tid + j * 256 + k;   // padded index: column (tid+j*256) + k - 5, +5 pad
                float p = sp[x], t = st[x];
                h0[j] += w * p;
                h1[j] += w * t;
                h2[j] += w * (p * p);
                h3[j] += w * (t * t);
                h4[j] += w * (p * t);
            }
        }

        // Vertical accumulation into the output rows this input row touches.
        #pragma unroll
        for (int r = 0; r < BH; ++r) {
            int dy = iy - y0 - r;
            if (dy >= -5 && dy <= 5) {       // uniform per block
                float wv = g[dy + 5];
                #pragma unroll
                for (int j = 0; j < 2; ++j) {
                    a0[r][j] += wv * h0[j];
                    a1[r][j] += wv * h1[j];
                    a2[r][j] += wv * h2[j];
                    a3[r][j] += wv * h3[j];
                    a4[r][j] += wv * h4[j];
                }
            }
        }
    }

    // SSIM map + partial sum.
    const float C1 = 1e-4f, C2 = 9e-4f;
    float sum = 0.f;
    #pragma unroll
    for (int r = 0; r < BH; ++r) {
        #pragma unroll
        for (int j = 0; j < 2; ++j) {
            float mu1 = a0[r][j], mu2 = a1[r][j];
            float mu1s = mu1 * mu1, mu2s = mu2 * mu2, mu12 = mu1 * mu2;
            float s1 = a2[r][j] - mu1s;
            float s2 = a3[r][j] - mu2s;
            float s12 = a4[r][j] - mu12;
            float num = (2.f * mu12 + C1) * (2.f * s12 + C2);
            float den = (mu1s + mu2s + C1) * (s1 + s2 + C2);
            sum += num / den;
        }
    }

    // Wave (64-lane) reduce, then block reduce, then one atomic per block.
    #pragma unroll
    for (int off = 32; off > 0; off >>= 1) sum += __shfl_down(sum, off, 64);
    __shared__ float wsum[4];
    int wave = tid >> 6, lane = tid & 63;
    if (lane == 0) wsum[wave] = sum;
    __syncthreads();
    if (tid == 0) {
        atomicAdd(acc, wsum[0] + wsum[1] + wsum[2] + wsum[3]);
    }
}

__global__ void ssim_final(const float* __restrict__ acc, float* __restrict__ out) {
    out[0] = 0.1f * (1.0f - acc[0] / NPIX);
}

extern "C" void kernel_launch(void* const* d_in, const int* in_sizes, int n_in,
                              void* d_out, int out_size, void* d_ws, size_t ws_size,
                              hipStream_t stream) {
    const float* pred = (const float*)d_in[0];
    const float* targ = (const float*)d_in[1];
    const float* win  = (const float*)d_in[2];
    float* out = (float*)d_out;
    float* acc = (float*)d_ws;

    hipMemsetAsync(acc, 0, sizeof(float), stream);   // fresh accumulator every call
    ssim_main<<<NPLANES * (H / BH), 256, 0, stream>>>(pred, targ, win, acc);
    ssim_final<<<1, 1, 0, stream>>>(acc, out);
}

// Round 2
// 122.841 us; speedup vs baseline: 1.1164x; 1.1164x over previous
//
#include <hip/hip_runtime.h>

#define BH 8
#define ROWS 18            // BH + 10 halo rows
#define W 512
#define H 512
#define LW 528             // 8 left pad + 512 + 8 right pad (16B-aligned data start)
#define NPLANES 48         // 16 batches * 3 channels
#define NPIX (16.0f*3.0f*512.0f*512.0f)

__global__ __launch_bounds__(256) void ssim_main(const float* __restrict__ pred,
                                                 const float* __restrict__ targ,
                                                 const float* __restrict__ win,
                                                 float* __restrict__ acc) {
    const int tid = threadIdx.x;
    const int strip = blockIdx.x & 63;       // 512/BH strips per plane
    const int nc = blockIdx.x >> 6;          // plane index 0..47
    const int y0 = strip * BH;
    const float* P = pred + (size_t)nc * (W * H);
    const float* T = targ + (size_t)nc * (W * H);

    // Recover 1D gaussian from 2D window: w2d[5][i] = g[5]*g[i].
    float g[11];
    {
        float g5 = sqrtf(win[60]);           // win[5*11+5] = g5^2
        #pragma unroll
        for (int i = 0; i < 11; ++i) g[i] = win[55 + i] / g5;
    }

    // Full working set staged once: 2 * 18 * 528 * 4B = 76 KB -> 2 blocks/CU.
    __shared__ float sp[ROWS][LW];
    __shared__ float st[ROWS][LW];

    // Zero the 8-wide column pads (left [0..7], right [520..527]) for all rows.
    for (int i = tid; i < ROWS * 16 * 2; i += 256) {
        int arr = i / (ROWS * 16);
        int k = i % (ROWS * 16);
        int row = k >> 4, o = k & 15;
        int col = (o < 8) ? o : (o + 512);
        (arr ? st : sp)[row][col] = 0.f;
    }

    // Stage all 18 rows with float4 loads; out-of-range rows stage zeros.
    #pragma unroll
    for (int i = 0; i < 9; ++i) {
        int linear = i * 256 + tid;          // [0, 18*128)
        int row = linear >> 7;               // 128 float4 per row
        int c4 = linear & 127;
        int iy = y0 - 5 + row;
        float4 vp = make_float4(0.f, 0.f, 0.f, 0.f);
        float4 vt = vp;
        if (iy >= 0 && iy < H) {
            vp = *(const float4*)(P + iy * W + c4 * 4);
            vt = *(const float4*)(T + iy * W + c4 * 4);
        }
        *(float4*)&sp[row][8 + c4 * 4] = vp;   // byte offset 32 + 64*c4: aligned
        *(float4*)&st[row][8 + c4 * 4] = vt;
    }
    __syncthreads();                          // the only barrier before epilogue

    // Per-thread accumulators: 5 fields x BH rows x 2 columns.
    float a0[BH][2], a1[BH][2], a2[BH][2], a3[BH][2], a4[BH][2];
    #pragma unroll
    for (int r = 0; r < BH; ++r)
        #pragma unroll
        for (int j = 0; j < 2; ++j) {
            a0[r][j] = 0.f; a1[r][j] = 0.f; a2[r][j] = 0.f;
            a3[r][j] = 0.f; a4[r][j] = 0.f;
        }

    // Skip rows that were staged as zeros (only affects the 2 edge strips).
    const int r0 = (y0 >= 5) ? 0 : (5 - y0);
    const int r1 = (y0 + BH + 4 < H) ? ROWS : (H + 5 - y0);

    for (int row = r0; row < r1; ++row) {
        float h0[2] = {0.f, 0.f}, h1[2] = {0.f, 0.f}, h2[2] = {0.f, 0.f},
              h3[2] = {0.f, 0.f}, h4[2] = {0.f, 0.f};
        #pragma unroll
        for (int k = 0; k < 11; ++k) {
            float w = g[k];
            #pragma unroll
            for (int j = 0; j < 2; ++j) {
                int x = tid + j * 256 + k + 3;   // 8 + (col + k - 5)
                float p = sp[row][x], t = st[row][x];
                float wp = w * p, wt = w * t;
                h0[j] += wp;
                h1[j] += wt;
                h2[j] += wp * p;
                h3[j] += wt * t;
                h4[j] += wp * t;
            }
        }
        #pragma unroll
        for (int r = 0; r < BH; ++r) {
            int wi = row - r;                    // g index for dy = row-5-r
            if (wi >= 0 && wi <= 10) {           // uniform per block
                float wv = g[wi];
                #pragma unroll
                for (int j = 0; j < 2; ++j) {
                    a0[r][j] += wv * h0[j];
                    a1[r][j] += wv * h1[j];
                    a2[r][j] += wv * h2[j];
                    a3[r][j] += wv * h3[j];
                    a4[r][j] += wv * h4[j];
                }
            }
        }
    }

    // SSIM map + partial sum.
    const float C1 = 1e-4f, C2 = 9e-4f;
    float sum = 0.f;
    #pragma unroll
    for (int r = 0; r < BH; ++r) {
        #pragma unroll
        for (int j = 0; j < 2; ++j) {
            float mu1 = a0[r][j], mu2 = a1[r][j];
            float mu1s = mu1 * mu1, mu2s = mu2 * mu2, mu12 = mu1 * mu2;
            float s1 = a2[r][j] - mu1s;
            float s2 = a3[r][j] - mu2s;
            float s12 = a4[r][j] - mu12;
            float num = (2.f * mu12 + C1) * (2.f * s12 + C2);
            float den = (mu1s + mu2s + C1) * (s1 + s2 + C2);
            sum += num / den;
        }
    }

    // Wave reduce -> block reduce -> one atomic per block.
    #pragma unroll
    for (int off = 32; off > 0; off >>= 1) sum += __shfl_down(sum, off, 64);
    __shared__ float wsum[4];
    int wave = tid >> 6, lane = tid & 63;
    if (lane == 0) wsum[wave] = sum;
    __syncthreads();
    if (tid == 0) {
        atomicAdd(acc, wsum[0] + wsum[1] + wsum[2] + wsum[3]);
    }
}

__global__ void ssim_final(const float* __restrict__ acc, float* __restrict__ out) {
    out[0] = 0.1f * (1.0f - acc[0] / NPIX);
}

extern "C" void kernel_launch(void* const* d_in, const int* in_sizes, int n_in,
                              void* d_out, int out_size, void* d_ws, size_t ws_size,
                              hipStream_t stream) {
    const float* pred = (const float*)d_in[0];
    const float* targ = (const float*)d_in[1];
    const float* win  = (const float*)d_in[2];
    float* out = (float*)d_out;
    float* acc = (float*)d_ws;

    hipMemsetAsync(acc, 0, sizeof(float), stream);   // fresh accumulator every call
    ssim_main<<<NPLANES * (H / BH), 256, 0, stream>>>(pred, targ, win, acc);
    ssim_final<<<1, 1, 0, stream>>>(acc, out);
}

// Round 3
// 115.347 us; speedup vs baseline: 1.1890x; 1.0650x over previous
//
#include <hip/hip_runtime.h>

#define BH 8
#define ROWS 18            // BH + 10 halo rows
#define W 512
#define H 512
#define LROW 544           // plane row stride in floats (multiple of 32 banks)
#define PLANE (BH*LROW + 32)   // +32 slack for the 4*r skew
#define NPIX (16.0f*3.0f*512.0f*512.0f)

__global__ __launch_bounds__(256, 4) void ssim_main(const float* __restrict__ pred,
                                                    const float* __restrict__ targ,
                                                    const float* __restrict__ win,
                                                    float* __restrict__ acc) {
    const int tid = threadIdx.x;
    const int strip = blockIdx.x & 63;       // 64 strips per plane
    const int nc = blockIdx.x >> 6;          // plane 0..47
    const int y0 = strip * BH;
    const float* P = pred + (size_t)nc * (W * H);
    const float* T = targ + (size_t)nc * (W * H);

    // 1D gaussian from 2D window: w2d[5][i] = g[5]*g[i].
    float g[11];
    {
        float g5 = sqrtf(win[60]);
        #pragma unroll
        for (int i = 0; i < 11; ++i) g[i] = win[55 + i] / g5;
    }

    __shared__ __align__(16) float pA[PLANE];
    __shared__ __align__(16) float pB[PLANE];
    __shared__ float wsum[4];

    // Zero the column pads once: per row, idx {0..7} (cols -5..-1) and
    // {520..527} (cols 512..516+). Skew = 4*r. Pads survive both rounds.
    {
        int r = (tid >> 4) & 7, o = tid & 15;
        int idx = r * LROW + 4 * r + ((o < 8) ? o : (o - 8 + 520));
        if (tid < 128) pA[idx] = 0.f;
        else           pB[idx] = 0.f;
    }

    // ---- Phase 1: vertical 11-tap conv, global -> registers. ----
    // Thread owns cols (tid, tid+256) for all 8 output rows.
    float vm1[BH][2], vm2[BH][2], vq[BH][2], vpt[BH][2];
    #pragma unroll
    for (int r = 0; r < BH; ++r) {
        vm1[r][0] = 0.f; vm1[r][1] = 0.f;
        vm2[r][0] = 0.f; vm2[r][1] = 0.f;
        vq [r][0] = 0.f; vq [r][1] = 0.f;
        vpt[r][0] = 0.f; vpt[r][1] = 0.f;
    }

    #pragma unroll
    for (int row = 0; row < ROWS; ++row) {
        const int iy = y0 - 5 + row;
        float p0 = 0.f, p1 = 0.f, t0 = 0.f, t1 = 0.f;
        if (iy >= 0 && iy < H) {             // uniform per block
            const float* pr = P + iy * W;
            const float* tr = T + iy * W;
            p0 = pr[tid]; p1 = pr[tid + 256];
            t0 = tr[tid]; t1 = tr[tid + 256];
        }
        const float q0 = fmaf(t0, t0, p0 * p0), q1 = fmaf(t1, t1, p1 * p1);
        const float x0 = p0 * t0, x1 = p1 * t1;
        #pragma unroll
        for (int r = 0; r < BH; ++r) {
            const int wi = row - r;          // g index for dy = row-5-r
            if (wi >= 0 && wi <= 10) {       // compile-time per (row,r)
                const float wv = g[wi];
                vm1[r][0] = fmaf(wv, p0, vm1[r][0]); vm1[r][1] = fmaf(wv, p1, vm1[r][1]);
                vm2[r][0] = fmaf(wv, t0, vm2[r][0]); vm2[r][1] = fmaf(wv, t1, vm2[r][1]);
                vq [r][0] = fmaf(wv, q0, vq [r][0]); vq [r][1] = fmaf(wv, q1, vq [r][1]);
                vpt[r][0] = fmaf(wv, x0, vpt[r][0]); vpt[r][1] = fmaf(wv, x1, vpt[r][1]);
            }
        }
    }

    // ---- Phase 2: horizontal 11-tap conv via LDS, 2 field-planes/round. ----
    // Reader thread: row r2 = tid&7, 16-col segment s = tid>>3 (banks spread
    // because skew 4*r2 varies across the wave's 8 r2 values).
    const int r2 = tid & 7, s = tid >> 3;
    const int rbase = r2 * LROW + 4 * r2 + 16 * s;

    float h0[16], h1[16], h2[16], h3[16];

#define WRITE_FIELD(plane, V)                                      \
    {                                                              \
        _Pragma("unroll")                                          \
        for (int r = 0; r < BH; ++r) {                             \
            const int base = r * LROW + 4 * r + 8;                 \
            plane[base + tid]       = V[r][0];                     \
            plane[base + tid + 256] = V[r][1];                     \
        }                                                          \
    }

#define HCONV(plane, Hout)                                         \
    {                                                              \
        float L[32];                                               \
        _Pragma("unroll")                                          \
        for (int wq = 0; wq < 8; ++wq)                             \
            *(float4*)&L[4 * wq] =                                 \
                *(const float4*)&plane[rbase + 4 * wq];            \
        _Pragma("unroll")                                          \
        for (int i = 0; i < 16; ++i) {                             \
            float hh = g[0] * L[i + 3];                            \
            _Pragma("unroll")                                      \
            for (int k = 1; k < 11; ++k)                           \
                hh = fmaf(g[k], L[i + 3 + k], hh);                 \
            Hout[i] = hh;                                          \
        }                                                          \
    }

    WRITE_FIELD(pA, vm1)
    WRITE_FIELD(pB, vm2)
    __syncthreads();
    HCONV(pA, h0)
    HCONV(pB, h1)
    __syncthreads();                 // reads done before overwrite
    WRITE_FIELD(pA, vq)
    WRITE_FIELD(pB, vpt)
    __syncthreads();
    HCONV(pA, h2)
    HCONV(pB, h3)

    // ---- SSIM map + partial sum (16 px per thread). ----
    const float C1 = 1e-4f, C2 = 9e-4f;
    float sum = 0.f;
    #pragma unroll
    for (int i = 0; i < 16; ++i) {
        const float mu1 = h0[i], mu2 = h1[i];
        const float ms  = fmaf(mu1, mu1, mu2 * mu2);   // mu1^2 + mu2^2
        const float m12 = mu1 * mu2;
        const float s12 = h3[i] - m12;                 // sigma12
        const float ssm = h2[i] - ms;                  // sigma1^2 + sigma2^2
        const float num = fmaf(2.f, m12, C1) * fmaf(2.f, s12, C2);
        const float den = (ms + C1) * (ssm + C2);
        sum += num / den;
    }

    // Wave reduce -> block reduce -> one atomic per block.
    #pragma unroll
    for (int off = 32; off > 0; off >>= 1) sum += __shfl_down(sum, off, 64);
    const int wave = tid >> 6, lane = tid & 63;
    if (lane == 0) wsum[wave] = sum;
    __syncthreads();
    if (tid == 0) atomicAdd(acc, wsum[0] + wsum[1] + wsum[2] + wsum[3]);
}

__global__ void ssim_final(const float* __restrict__ acc, float* __restrict__ out) {
    out[0] = 0.1f * (1.0f - acc[0] / NPIX);
}

extern "C" void kernel_launch(void* const* d_in, const int* in_sizes, int n_in,
                              void* d_out, int out_size, void* d_ws, size_t ws_size,
                              hipStream_t stream) {
    const float* pred = (const float*)d_in[0];
    const float* targ = (const float*)d_in[1];
    const float* win  = (const float*)d_in[2];
    float* out = (float*)d_out;
    float* acc = (float*)d_ws;

    hipMemsetAsync(acc, 0, sizeof(float), stream);   // fresh accumulator each call
    ssim_main<<<48 * (H / BH), 256, 0, stream>>>(pred, targ, win, acc);
    ssim_final<<<1, 1, 0, stream>>>(acc, out);
}

// Round 4
// 67.218 us; speedup vs baseline: 2.0403x; 1.7160x over previous
//
#include <hip/hip_runtime.h>

#define BH 8
#define ROWS 18            // BH + 10 halo rows
#define W 512
#define H 512
#define RSTRIDE 548        // 544 (multiple of 32 banks) + 4-float per-row skew
#define PLANE 4384         // >= 7*548 + 528
#define NPIX (16.0f*3.0f*512.0f*512.0f)

__global__ __launch_bounds__(256) void ssim_main(const float* __restrict__ pred,
                                                 const float* __restrict__ targ,
                                                 const float* __restrict__ win,
                                                 float* __restrict__ acc) {
    const int tid = threadIdx.x;
    const int strip = blockIdx.x & 63;       // 64 strips per plane
    const int nc = blockIdx.x >> 6;          // plane 0..47
    const int y0 = strip * BH;
    const float* P = pred + (size_t)nc * (W * H);
    const float* T = targ + (size_t)nc * (W * H);

    // 1D gaussian from 2D window: w2d[5][i] = g[5]*g[i].
    float g[11];
    {
        float g5 = sqrtf(win[60]);
        #pragma unroll
        for (int i = 0; i < 11; ++i) g[i] = win[55 + i] / g5;
    }

    // Layout: idx(r, pc) = r*RSTRIDE + pc, pc = col + 8 (8-wide zero pads both sides).
    __shared__ __align__(16) float pA[PLANE];
    __shared__ __align__(16) float pB[PLANE];
    __shared__ float wsum[4];

    // Zero the column pads once (they survive both plane rounds).
    {
        const int r = (tid >> 4) & 7, o = tid & 15;
        const int idx = r * RSTRIDE + ((o < 8) ? o : (o + 512));
        if (tid < 128) pA[idx] = 0.f;
        else           pB[idx] = 0.f;
    }

    // ---- Phase 1: vertical 11-tap conv, global -> registers. ----
    // Thread owns cols (2*tid, 2*tid+1) for all 8 output rows.
    float vm1[BH][2], vm2[BH][2], vq[BH][2], vpt[BH][2];
    #pragma unroll
    for (int r = 0; r < BH; ++r) {
        vm1[r][0] = 0.f; vm1[r][1] = 0.f;
        vm2[r][0] = 0.f; vm2[r][1] = 0.f;
        vq [r][0] = 0.f; vq [r][1] = 0.f;
        vpt[r][0] = 0.f; vpt[r][1] = 0.f;
    }

    #pragma unroll
    for (int row = 0; row < ROWS; ++row) {
        const int iy = y0 - 5 + row;
        float2 pv = make_float2(0.f, 0.f), tv = make_float2(0.f, 0.f);
        if (iy >= 0 && iy < H) {             // uniform per block
            pv = *(const float2*)(P + iy * W + 2 * tid);
            tv = *(const float2*)(T + iy * W + 2 * tid);
        }
        const float q0 = fmaf(tv.x, tv.x, pv.x * pv.x);
        const float q1 = fmaf(tv.y, tv.y, pv.y * pv.y);
        const float x0 = pv.x * tv.x, x1 = pv.y * tv.y;
        #pragma unroll
        for (int r = 0; r < BH; ++r) {
            const int wi = row - r;          // g index for dy = row-5-r
            if (wi >= 0 && wi <= 10) {       // compile-time per (row,r)
                const float wv = g[wi];
                vm1[r][0] = fmaf(wv, pv.x, vm1[r][0]); vm1[r][1] = fmaf(wv, pv.y, vm1[r][1]);
                vm2[r][0] = fmaf(wv, tv.x, vm2[r][0]); vm2[r][1] = fmaf(wv, tv.y, vm2[r][1]);
                vq [r][0] = fmaf(wv, q0,   vq [r][0]); vq [r][1] = fmaf(wv, q1,   vq [r][1]);
                vpt[r][0] = fmaf(wv, x0,   vpt[r][0]); vpt[r][1] = fmaf(wv, x1,   vpt[r][1]);
            }
        }
    }

    // ---- Phase 2: horizontal 11-tap via LDS, 2 field-planes per round. ----
    // Reader: row r2 = tid&7, 16-col segment s = tid>>3.
    const int r2 = tid & 7, s = tid >> 3;
    const int rbase = r2 * RSTRIDE + 16 * s;   // pc 16s = col 16s-8; L[i+3+k] = tap k of px i

#define WRITE_FIELD(plane, V)                                          \
    {                                                                  \
        _Pragma("unroll")                                              \
        for (int r = 0; r < BH; ++r)                                   \
            *(float2*)&plane[r * RSTRIDE + 8 + 2 * tid] =              \
                make_float2(V[r][0], V[r][1]);                         \
    }

#define HCONV(plane, Hout)                                             \
    {                                                                  \
        float L[32];                                                   \
        _Pragma("unroll")                                              \
        for (int wq = 0; wq < 8; ++wq)                                 \
            *(float4*)&L[4 * wq] = *(const float4*)&plane[rbase + 4 * wq]; \
        _Pragma("unroll")                                              \
        for (int i = 0; i < 16; ++i) {                                 \
            float hh = g[0] * L[i + 3];                                \
            _Pragma("unroll")                                          \
            for (int k = 1; k < 11; ++k)                               \
                hh = fmaf(g[k], L[i + 3 + k], hh);                     \
            Hout[i] = hh;                                              \
        }                                                              \
    }

    float hq[16], hpt[16], hm1[16];

    WRITE_FIELD(pA, vq)
    WRITE_FIELD(pB, vpt)
    __syncthreads();
    HCONV(pA, hq)
    HCONV(pB, hpt)
    __syncthreads();                 // reads done before overwrite
    WRITE_FIELD(pA, vm1)
    WRITE_FIELD(pB, vm2)
    __syncthreads();
    HCONV(pA, hm1)

    // Last field (mu2) folded per-pixel into the SSIM epilogue.
    const float C1 = 1e-4f, C2 = 9e-4f;
    float sum = 0.f;
    {
        float L[32];
        #pragma unroll
        for (int wq = 0; wq < 8; ++wq)
            *(float4*)&L[4 * wq] = *(const float4*)&pB[rbase + 4 * wq];
        #pragma unroll
        for (int i = 0; i < 16; ++i) {
            float mu2 = g[0] * L[i + 3];
            #pragma unroll
            for (int k = 1; k < 11; ++k)
                mu2 = fmaf(g[k], L[i + 3 + k], mu2);
            const float mu1 = hm1[i];
            const float ms  = fmaf(mu1, mu1, mu2 * mu2);   // mu1^2 + mu2^2
            const float m12 = mu1 * mu2;
            const float s12 = hpt[i] - m12;                // sigma12
            const float ssm = hq[i] - ms;                  // sigma1^2 + sigma2^2
            const float num = fmaf(2.f, m12, C1) * fmaf(2.f, s12, C2);
            const float den = (ms + C1) * (ssm + C2);
            sum += num * __builtin_amdgcn_rcpf(den);
        }
    }

    // Wave reduce -> block reduce -> one atomic per block.
    #pragma unroll
    for (int off = 32; off > 0; off >>= 1) sum += __shfl_down(sum, off, 64);
    const int wave = tid >> 6, lane = tid & 63;
    if (lane == 0) wsum[wave] = sum;
    __syncthreads();
    if (tid == 0) atomicAdd(acc, wsum[0] + wsum[1] + wsum[2] + wsum[3]);
}

__global__ void ssim_final(const float* __restrict__ acc, float* __restrict__ out) {
    out[0] = 0.1f * (1.0f - acc[0] / NPIX);
}

extern "C" void kernel_launch(void* const* d_in, const int* in_sizes, int n_in,
                              void* d_out, int out_size, void* d_ws, size_t ws_size,
                              hipStream_t stream) {
    const float* pred = (const float*)d_in[0];
    const float* targ = (const float*)d_in[1];
    const float* win  = (const float*)d_in[2];
    float* out = (float*)d_out;
    float* acc = (float*)d_ws;

    hipMemsetAsync(acc, 0, sizeof(float), stream);   // fresh accumulator each call
    ssim_main<<<48 * (H / BH), 256, 0, stream>>>(pred, targ, win, acc);
    ssim_final<<<1, 1, 0, stream>>>(acc, out);
}

// Round 5
// 57.656 us; speedup vs baseline: 2.3786x; 1.1658x over previous
//
#include <hip/hip_runtime.h>

#define BH 8
#define ROWS 18            // BH + 10 halo rows
#define W 512
#define H 512
#define RSTRIDE 548        // row stride in floats: 544 (17*32) + 4 skew
#define PLANE 4384         // >= 7*548 + 528, 16B-aligned slack
#define NPIX (16.0f*3.0f*512.0f*512.0f)
#define NACC 64

__global__ __launch_bounds__(512) void ssim_main(const float* __restrict__ pred,
                                                 const float* __restrict__ targ,
                                                 const float* __restrict__ win,
                                                 float* __restrict__ acc) {
    const int tid = threadIdx.x;             // 0..511 = column
    const int strip = blockIdx.x & 63;       // 64 strips per plane
    const int nc = blockIdx.x >> 6;          // plane 0..47
    const int y0 = strip * BH;
    const float* P = pred + (size_t)nc * (W * H);
    const float* T = targ + (size_t)nc * (W * H);

    // 1D gaussian from 2D window (w2d[5][i] = g[5]*g[i]), broadcast to SGPRs.
    float g[11];
    {
        const float inv = __builtin_amdgcn_rcpf(sqrtf(win[60]));
        #pragma unroll
        for (int i = 0; i < 11; ++i)
            g[i] = __int_as_float(
                __builtin_amdgcn_readfirstlane(__float_as_int(win[55 + i] * inv)));
    }

    // Single field plane; pc = col + 8, 8-wide zero pads both sides.
    __shared__ __align__(16) float pl[PLANE];
    __shared__ float wsum[8];

    if (tid < 128) {                         // zero pads once (survive all rounds)
        const int r = tid >> 4, o = tid & 15;
        pl[r * RSTRIDE + ((o < 8) ? o : (o + 512))] = 0.f;
    }

    // ---- Phase 1: vertical 11-tap conv, global -> registers (1 col/thread). ----
    float vm1[BH], vm2[BH], vq[BH], vpt[BH];
    #pragma unroll
    for (int r = 0; r < BH; ++r) { vm1[r] = 0.f; vm2[r] = 0.f; vq[r] = 0.f; vpt[r] = 0.f; }

    #pragma unroll
    for (int row = 0; row < ROWS; ++row) {
        const int iy = y0 - 5 + row;
        float p = 0.f, t = 0.f;
        if (iy >= 0 && iy < H) {             // uniform per block
            p = P[iy * W + tid];
            t = T[iy * W + tid];
        }
        const float q = fmaf(t, t, p * p);
        const float x = p * t;
        #pragma unroll
        for (int r = 0; r < BH; ++r) {
            const int wi = row - r;          // weight index, compile-time per (row,r)
            if (wi >= 0 && wi <= 10) {
                const float wv = g[wi];
                vm1[r] = fmaf(wv, p, vm1[r]);
                vm2[r] = fmaf(wv, t, vm2[r]);
                vq [r] = fmaf(wv, q, vq [r]);
                vpt[r] = fmaf(wv, x, vpt[r]);
            }
        }
    }

    // ---- Phase 2: horizontal 11-tap via LDS, one field per round. ----
    // Reader: row r2 = tid&7, 8-col segment s = tid>>3 (cols 8s..8s+7).
    const int r2 = tid & 7, s = tid >> 3;
    const int rbase = r2 * RSTRIDE + 8 * s;  // 16B-aligned; L[j] = pl[rbase+j]

#define WRITE_F(V)                                                     \
    {                                                                  \
        _Pragma("unroll")                                              \
        for (int r = 0; r < BH; ++r)                                   \
            pl[r * RSTRIDE + 8 + tid] = V[r];                          \
    }

#define HCONV_F(Hout)                                                  \
    {                                                                  \
        float L[24];                                                   \
        _Pragma("unroll")                                              \
        for (int wq = 0; wq < 6; ++wq)                                 \
            *(float4*)&L[4 * wq] = *(const float4*)&pl[rbase + 4 * wq];\
        _Pragma("unroll")                                              \
        for (int i = 0; i < 8; ++i) {                                  \
            float hh = g[0] * L[i + 3];                                \
            _Pragma("unroll")                                          \
            for (int k = 1; k < 11; ++k)                               \
                hh = fmaf(g[k], L[i + 3 + k], hh);                     \
            Hout[i] = hh;                                              \
        }                                                              \
    }

    float hq[8], hpt[8], hm1[8];

    __syncthreads();
    WRITE_F(vq)
    __syncthreads();
    HCONV_F(hq)
    __syncthreads();
    WRITE_F(vpt)
    __syncthreads();
    HCONV_F(hpt)
    __syncthreads();
    WRITE_F(vm1)
    __syncthreads();
    HCONV_F(hm1)
    __syncthreads();
    WRITE_F(vm2)
    __syncthreads();

    // Last field (mu2) folded per-pixel into the SSIM epilogue.
    const float C1 = 1e-4f, C2 = 9e-4f;
    float sum = 0.f;
    {
        float L[24];
        #pragma unroll
        for (int wq = 0; wq < 6; ++wq)
            *(float4*)&L[4 * wq] = *(const float4*)&pl[rbase + 4 * wq];
        #pragma unroll
        for (int i = 0; i < 8; ++i) {
            float mu2 = g[0] * L[i + 3];
            #pragma unroll
            for (int k = 1; k < 11; ++k)
                mu2 = fmaf(g[k], L[i + 3 + k], mu2);
            const float mu1 = hm1[i];
            const float ms  = fmaf(mu1, mu1, mu2 * mu2);   // mu1^2 + mu2^2
            const float m12 = mu1 * mu2;
            const float s12 = hpt[i] - m12;                // sigma12
            const float ssm = hq[i] - ms;                  // sigma1^2 + sigma2^2
            const float num = fmaf(2.f, m12, C1) * fmaf(2.f, s12, C2);
            const float den = (ms + C1) * (ssm + C2);
            sum += num * __builtin_amdgcn_rcpf(den);
        }
    }

    // Wave reduce -> block reduce -> one atomic per block (64 slots).
    #pragma unroll
    for (int off = 32; off > 0; off >>= 1) sum += __shfl_down(sum, off, 64);
    const int wave = tid >> 6, lane = tid & 63;
    if (lane == 0) wsum[wave] = sum;
    __syncthreads();
    if (tid == 0) {
        float b = 0.f;
        #pragma unroll
        for (int w = 0; w < 8; ++w) b += wsum[w];
        atomicAdd(&acc[blockIdx.x & (NACC - 1)], b);
    }
}

__global__ void ssim_final(const float* __restrict__ acc, float* __restrict__ out) {
    float s = 0.f;
    #pragma unroll
    for (int i = 0; i < NACC; ++i) s += acc[i];
    out[0] = 0.1f * (1.0f - s / NPIX);
}

extern "C" void kernel_launch(void* const* d_in, const int* in_sizes, int n_in,
                              void* d_out, int out_size, void* d_ws, size_t ws_size,
                              hipStream_t stream) {
    const float* pred = (const float*)d_in[0];
    const float* targ = (const float*)d_in[1];
    const float* win  = (const float*)d_in[2];
    float* out = (float*)d_out;
    float* acc = (float*)d_ws;

    hipMemsetAsync(acc, 0, NACC * sizeof(float), stream);  // fresh accumulators
    ssim_main<<<48 * (H / BH), 512, 0, stream>>>(pred, targ, win, acc);
    ssim_final<<<1, 1, 0, stream>>>(acc, out);
}

// Round 6
// 46.926 us; speedup vs baseline: 2.9225x; 1.2287x over previous
//
#include <hip/hip_runtime.h>

typedef _Float16 half8 __attribute__((ext_vector_type(8)));
typedef float f32x4 __attribute__((ext_vector_type(4)));

#define W 512
#define H 512
#define NPIX (16.0f*3.0f*512.0f*512.0f)
#define NACC 64
#define VSTR 88                 // V-plane col stride (fp16): 176 B, 16B-aligned rows
#define VPLANE (64*VSTR)        // per-field V-plane elements

__global__ __launch_bounds__(256) void ssim_main(const float* __restrict__ pred,
                                                 const float* __restrict__ targ,
                                                 const float* __restrict__ win,
                                                 float* __restrict__ acc) {
    const int tid  = threadIdx.x;
    const int lane = tid & 63;
    const int wv   = tid >> 6;          // wave 0..3 = row-tile
    const int lo   = lane & 15;
    const int hi   = lane >> 4;

    // XCD-aware swizzle (bijective: 3072 % 8 == 0): each XCD gets 384 contiguous tiles.
    const int b = (blockIdx.x & 7) * 384 + (blockIdx.x >> 3);
    const int sx = b & 7, sy = (b >> 3) & 7, nc = b >> 6;
    const int x0 = sx * 64, y0 = sy * 64;
    const float* P = pred + (size_t)nc * (W * H);
    const float* T = targ + (size_t)nc * (W * H);

    __shared__ __align__(16) _Float16 VP[4 * VPLANE];  // 0:mu1 1:mu2 2:q 3:pt
    __shared__ _Float16 gw[64];
    __shared__ float wsum[4];

    // Weight table: gw[i] = g[i-18] for i in [18,28], else 0.  g = row 5 of the
    // 2D window / sqrt(center) (w2d[5][i] = g5*g[i], w2d[5][5] = g5^2).
    if (tid < 64) {
        const int d = tid - 18;
        float val = 0.f;
        if (d >= 0 && d <= 10)
            val = win[55 + d] * __builtin_amdgcn_rcpf(sqrtf(win[60]));
        gw[tid] = (_Float16)val;
    }
    __syncthreads();

    // One-time weight fragments (same assumed k-map as the data fragments:
    // k = hi*8 + j, so any true k-permutation cancels between A and B).
    half8 Aw, Bw;                        // V-pass A (row m=lo), H-pass B (col n=lo)
    #pragma unroll
    for (int j = 0; j < 8; ++j) {
        Aw[j] = gw[18 + hi * 8 + j - lo];   // g[k - m]
        Bw[j] = gw[15 + hi * 8 + j - lo];   // g[k - n - 3]
    }

    const f32x4 zero4 = {0.f, 0.f, 0.f, 0.f};

    // ---- V-pass: 5 col-tiles per wave; B-fragments straight from global. ----
    #pragma unroll
    for (int tc5 = 0; tc5 < 5; ++tc5) {
        const int col   = x0 - 8 + 16 * tc5 + lo;     // image col for this lane
        const int rbase = y0 - 5 + 16 * wv + hi * 8;  // first of 8 image rows
        float pf[8], tf[8];
        const bool fastpos = (y0 - 5 + 16 * wv >= 0) && (y0 - 5 + 16 * wv + 31 < H)
                          && (x0 - 8 + 16 * tc5 >= 0) && (x0 - 8 + 16 * tc5 + 15 < W);
        if (fastpos) {                                 // wave-uniform branch
            const float* Pp = P + (size_t)rbase * W + col;
            const float* Tp = T + (size_t)rbase * W + col;
            #pragma unroll
            for (int j = 0; j < 8; ++j) { pf[j] = Pp[j * W]; tf[j] = Tp[j * W]; }
        } else {
            const bool cok = (unsigned)col < W;
            const int  ccl = cok ? col : 0;
            #pragma unroll
            for (int j = 0; j < 8; ++j) {
                const int  r   = rbase + j;
                const bool rok = (unsigned)r < H;
                const int  rcl = rok ? r : 0;
                const float pv = P[(size_t)rcl * W + ccl];
                const float tv = T[(size_t)rcl * W + ccl];
                pf[j] = (rok && cok) ? pv : 0.f;       // zero padding
                tf[j] = (rok && cok) ? tv : 0.f;
            }
        }
        half8 pa, ta, qa, xa;
        #pragma unroll
        for (int j = 0; j < 8; ++j) {
            pa[j] = (_Float16)pf[j];
            ta[j] = (_Float16)tf[j];
            qa[j] = (_Float16)fmaf(tf[j], tf[j], pf[j] * pf[j]);  // q = p^2+t^2 (f32, 1 rounding)
            xa[j] = (_Float16)(pf[j] * tf[j]);                    // x = p*t
        }
        const f32x4 d0 = __builtin_amdgcn_mfma_f32_16x16x32_f16(Aw, pa, zero4, 0, 0, 0);
        const f32x4 d1 = __builtin_amdgcn_mfma_f32_16x16x32_f16(Aw, ta, zero4, 0, 0, 0);
        const f32x4 d2 = __builtin_amdgcn_mfma_f32_16x16x32_f16(Aw, qa, zero4, 0, 0, 0);
        const f32x4 d3 = __builtin_amdgcn_mfma_f32_16x16x32_f16(Aw, xa, zero4, 0, 0, 0);
        // Store V tiles: row = 16*wv + hi*4 + reg, col = 16*tc5 + lo (C/D layout, m89).
        const int vcol = 16 * tc5 + lo;
        #pragma unroll
        for (int reg = 0; reg < 4; ++reg) {
            const int base = (16 * wv + hi * 4 + reg) * VSTR + vcol;
            VP[0 * VPLANE + base] = (_Float16)d0[reg];
            VP[1 * VPLANE + base] = (_Float16)d1[reg];
            VP[2 * VPLANE + base] = (_Float16)d2[reg];
            VP[3 * VPLANE + base] = (_Float16)d3[reg];
        }
    }
    __syncthreads();

    // ---- H-pass + SSIM epilogue: 4 col-tiles per wave. ----
    const float C1 = 1e-4f, C2 = 9e-4f;
    float sum = 0.f;
    #pragma unroll
    for (int tc2 = 0; tc2 < 4; ++tc2) {
        // A[m][k]: row = 16*wv + lo, cc = 16*tc2 + hi*8 + j  (one b128 per field)
        const int ai = (16 * wv + lo) * VSTR + 16 * tc2 + hi * 8;
        const half8 a0 = *(const half8*)&VP[0 * VPLANE + ai];
        const half8 a1 = *(const half8*)&VP[1 * VPLANE + ai];
        const half8 a2 = *(const half8*)&VP[2 * VPLANE + ai];
        const half8 a3 = *(const half8*)&VP[3 * VPLANE + ai];
        const f32x4 m1 = __builtin_amdgcn_mfma_f32_16x16x32_f16(a0, Bw, zero4, 0, 0, 0);
        const f32x4 m2 = __builtin_amdgcn_mfma_f32_16x16x32_f16(a1, Bw, zero4, 0, 0, 0);
        const f32x4 qq = __builtin_amdgcn_mfma_f32_16x16x32_f16(a2, Bw, zero4, 0, 0, 0);
        const f32x4 pt = __builtin_amdgcn_mfma_f32_16x16x32_f16(a3, Bw, zero4, 0, 0, 0);
        #pragma unroll
        for (int r = 0; r < 4; ++r) {
            const float mu1 = m1[r], mu2 = m2[r];
            const float ms  = fmaf(mu1, mu1, mu2 * mu2);   // mu1^2 + mu2^2
            const float m12 = mu1 * mu2;
            const float s12 = pt[r] - m12;                 // sigma12
            const float ssm = qq[r] - ms;                  // sigma1^2 + sigma2^2
            const float num = fmaf(2.f, m12, C1) * fmaf(2.f, s12, C2);
            const float den = (ms + C1) * (ssm + C2);
            sum += num * __builtin_amdgcn_rcpf(den);
        }
    }

    // Wave reduce -> block reduce -> one atomic per block (64 slots).
    #pragma unroll
    for (int off = 32; off > 0; off >>= 1) sum += __shfl_down(sum, off, 64);
    if (lane == 0) wsum[wv] = sum;
    __syncthreads();
    if (tid == 0)
        atomicAdd(&acc[blockIdx.x & (NACC - 1)], wsum[0] + wsum[1] + wsum[2] + wsum[3]);
}

__global__ void ssim_final(const float* __restrict__ acc, float* __restrict__ out) {
    float s = 0.f;
    #pragma unroll
    for (int i = 0; i < NACC; ++i) s += acc[i];
    out[0] = 0.1f * (1.0f - s / NPIX);
}

extern "C" void kernel_launch(void* const* d_in, const int* in_sizes, int n_in,
                              void* d_out, int out_size, void* d_ws, size_t ws_size,
                              hipStream_t stream) {
    const float* pred = (const float*)d_in[0];
    const float* targ = (const float*)d_in[1];
    const float* win  = (const float*)d_in[2];
    float* out = (float*)d_out;
    float* acc = (float*)d_ws;

    hipMemsetAsync(acc, 0, NACC * sizeof(float), stream);  // fresh accumulators
    ssim_main<<<3072, 256, 0, stream>>>(pred, targ, win, acc);
    ssim_final<<<1, 1, 0, stream>>>(acc, out);
}